// Round 1
// baseline (874.500 us; speedup 1.0000x reference)
//
#include <hip/hip_runtime.h>
#include <hip/hip_bf16.h>

#define N_NODES 20000
#define E_EDGES 640000
#define DIM 128
#define CAP 192
#define XST 264   // padded ushort stride for [32][256] LDS tiles
#define A2ST 136  // padded stride for a2 tile

typedef __attribute__((ext_vector_type(8))) short bf16x8;
typedef __attribute__((ext_vector_type(4))) float f32x4;

__device__ __forceinline__ float fsilu(float x) { return x / (1.f + __expf(-x)); }
__device__ __forceinline__ float fsig(float x)  { return 1.f / (1.f + __expf(-x)); }

__device__ __forceinline__ unsigned short f2bf(float x) {
    union { float f; unsigned u; } v; v.f = x;
    unsigned r = (v.u + 0x7fffu + ((v.u >> 16) & 1u)) >> 16;
    return (unsigned short)r;
}
__device__ __forceinline__ float bf2f(unsigned short s) {
    union { unsigned u; float f; } v; v.u = ((unsigned)s) << 16;
    return v.f;
}

// ---------------- Kernel 0: weight prep (fp32 -> bf16) ----------------
__global__ void prep_kernel(const float* __restrict__ w1, const float* __restrict__ w2,
                            unsigned short* __restrict__ w1b, float* __restrict__ w1last,
                            unsigned short* __restrict__ w2b) {
    int i = blockIdx.x * blockDim.x + threadIdx.x;
    int stride = gridDim.x * blockDim.x;
    for (int idx = i; idx < 256 * 256; idx += stride) {
        int o = idx >> 8, k = idx & 255;
        w1b[idx] = f2bf(w1[o * 257 + k]);
    }
    for (int idx = i; idx < 128 * 256; idx += stride)
        w2b[idx] = f2bf(w2[idx]);
    for (int idx = i; idx < 256; idx += stride)
        w1last[idx] = w1[idx * 257 + 256];
}

// ---------------- Kernel 1: x = h @ lin_w.T + lin_b (fp32 + bf16 copy) ----------------
__global__ void lin_kernel(const float* __restrict__ h, const float* __restrict__ w,
                           const float* __restrict__ b, float* __restrict__ x,
                           unsigned short* __restrict__ xb) {
    __shared__ float hs[8][128];
    int t = threadIdx.x;            // 128 threads = output channel
    int n0 = blockIdx.x * 8;
    for (int j = 0; j < 8; ++j) hs[j][t] = h[(size_t)(n0 + j) * DIM + t];
    __syncthreads();
    float acc[8] = {0, 0, 0, 0, 0, 0, 0, 0};
    for (int kc = 0; kc < 128; kc += 4) {
        float4 wv = *(const float4*)&w[(size_t)t * DIM + kc];
#pragma unroll
        for (int j = 0; j < 8; ++j)
            acc[j] += wv.x * hs[j][kc] + wv.y * hs[j][kc + 1] + wv.z * hs[j][kc + 2] + wv.w * hs[j][kc + 3];
    }
    float bias = b[t];
#pragma unroll
    for (int j = 0; j < 8; ++j) {
        float v = acc[j] + bias;
        x[(size_t)(n0 + j) * DIM + t] = v;
        xb[(size_t)(n0 + j) * DIM + t] = f2bf(v);
    }
}

// ---------------- Kernel 3: adjacency build ----------------
__global__ void adj_kernel(const int* __restrict__ edges, int* __restrict__ cnt,
                           int* __restrict__ adj, int E) {
    int e = blockIdx.x * blockDim.x + threadIdx.x;
    if (e < E) {
        int r = edges[e];  // row
        int slot = atomicAdd(&cnt[r], 1);
        if (slot < CAP) adj[(size_t)r * CAP + slot] = e;
    }
}

// ---------------- Kernel 2: edge MLP -> att[E] ----------------
// block = 256 threads (4 waves), 32 edges/block. Waves split N dim.
__global__ __launch_bounds__(256) void edge_kernel(
    const unsigned short* __restrict__ xb,
    const float* __restrict__ dist, const float* __restrict__ emask,
    const int* __restrict__ edges,
    const unsigned short* __restrict__ w1b, const float* __restrict__ w1last,
    const float* __restrict__ b1,
    const unsigned short* __restrict__ w2b, const float* __restrict__ b2,
    const float* __restrict__ w3, const float* __restrict__ b3v,
    float* __restrict__ att, int E) {
    __shared__ unsigned short smem[2 * 32 * XST];
    unsigned short* xcat = smem;             // [32][XST], cols 0..255 used
    unsigned short* a1s  = smem + 32 * XST;  // [32][XST]
    unsigned short* a2s  = smem;             // [32][A2ST] aliases xcat (safe: xcat dead after layer1)
    __shared__ float dvals[32];
    __shared__ int ridx[32], cidx[32];

    int tid = threadIdx.x;
    int eb = blockIdx.x * 32;

    if (tid < 32) {
        int e = eb + tid;
        ridx[tid] = edges[e];
        cidx[tid] = edges[E + e];
        dvals[tid] = dist[e] * emask[e];
    }
    __syncthreads();

    // gather x_cat = [x[row] | x[col]] as bf16, 16B chunks
#pragma unroll
    for (int i = 0; i < 4; ++i) {
        int c = tid + 256 * i;     // 0..1023 ; 32 chunks of 8 ushorts per row
        int r = c >> 5;
        int cb = (c & 31) * 8;
        const unsigned short* src;
        if (cb < 128) src = xb + (size_t)ridx[r] * DIM + cb;
        else          src = xb + (size_t)cidx[r] * DIM + (cb - 128);
        *(bf16x8*)&xcat[r * XST + cb] = *(const bf16x8*)src;
    }
    __syncthreads();

    int wave = tid >> 6, lane = tid & 63;
    int lrow = lane & 15, quad = lane >> 4;

    // ---- layer 1: a1 = silu(xcat @ W1^T + b1 + d*w1_last), wave covers 64 of 256 outputs
    f32x4 z = {0.f, 0.f, 0.f, 0.f};
    f32x4 acc1[2][4];
#pragma unroll
    for (int mt = 0; mt < 2; ++mt)
#pragma unroll
        for (int nt = 0; nt < 4; ++nt) acc1[mt][nt] = z;

    int nb = wave * 64;
    for (int kk = 0; kk < 8; ++kk) {
        int ka = kk * 32 + quad * 8;
        bf16x8 a0 = *(bf16x8*)&xcat[lrow * XST + ka];
        bf16x8 a1f = *(bf16x8*)&xcat[(16 + lrow) * XST + ka];
#pragma unroll
        for (int nt = 0; nt < 4; ++nt) {
            int n = nb + nt * 16 + lrow;
            bf16x8 bfrag = *(const bf16x8*)&w1b[(size_t)n * 256 + ka];
            acc1[0][nt] = __builtin_amdgcn_mfma_f32_16x16x32_bf16(a0, bfrag, acc1[0][nt], 0, 0, 0);
            acc1[1][nt] = __builtin_amdgcn_mfma_f32_16x16x32_bf16(a1f, bfrag, acc1[1][nt], 0, 0, 0);
        }
    }
#pragma unroll
    for (int nt = 0; nt < 4; ++nt) {
        int n = nb + nt * 16 + lrow;
        float bias = b1[n];
        float wl = w1last[n];
#pragma unroll
        for (int mt = 0; mt < 2; ++mt) {
#pragma unroll
            for (int r = 0; r < 4; ++r) {
                int m = mt * 16 + quad * 4 + r;
                float v = acc1[mt][nt][r] + bias + dvals[m] * wl;
                a1s[m * XST + n] = f2bf(fsilu(v));
            }
        }
    }
    __syncthreads();

    // ---- layer 2: a2 = silu(a1 @ W2^T + b2), wave covers 32 of 128 outputs
    f32x4 acc2[2][2];
#pragma unroll
    for (int mt = 0; mt < 2; ++mt)
#pragma unroll
        for (int nt = 0; nt < 2; ++nt) acc2[mt][nt] = z;

    int nb2 = wave * 32;
    for (int kk = 0; kk < 8; ++kk) {
        int ka = kk * 32 + quad * 8;
        bf16x8 a0 = *(bf16x8*)&a1s[lrow * XST + ka];
        bf16x8 a1f = *(bf16x8*)&a1s[(16 + lrow) * XST + ka];
#pragma unroll
        for (int nt = 0; nt < 2; ++nt) {
            int n = nb2 + nt * 16 + lrow;
            bf16x8 bfrag = *(const bf16x8*)&w2b[(size_t)n * 256 + ka];
            acc2[0][nt] = __builtin_amdgcn_mfma_f32_16x16x32_bf16(a0, bfrag, acc2[0][nt], 0, 0, 0);
            acc2[1][nt] = __builtin_amdgcn_mfma_f32_16x16x32_bf16(a1f, bfrag, acc2[1][nt], 0, 0, 0);
        }
    }
#pragma unroll
    for (int nt = 0; nt < 2; ++nt) {
        int n = nb2 + nt * 16 + lrow;
        float bias = b2[n];
#pragma unroll
        for (int mt = 0; mt < 2; ++mt) {
#pragma unroll
            for (int r = 0; r < 4; ++r) {
                int m = mt * 16 + quad * 4 + r;
                float v = acc2[mt][nt][r] + bias;
                a2s[m * A2ST + n] = f2bf(fsilu(v));
            }
        }
    }
    __syncthreads();

    // ---- layer 3: att = sigmoid(a2 . w3 + b3) * edge_mask
    if (tid < 32) {
        float s = 0.f;
        for (int n = 0; n < 128; ++n) s += bf2f(a2s[tid * A2ST + n]) * w3[n];
        att[eb + tid] = fsig(s + b3v[0]) * emask[eb + tid];
    }
}

// ---------------- Kernel 4: aggregate + node MLP + LNs ----------------
// block = 128 threads (thread = channel), 4 nodes per block
__global__ void node_kernel(
    const float* __restrict__ attv, const int* __restrict__ adj, const int* __restrict__ cnt,
    const int* __restrict__ edges, const unsigned short* __restrict__ xb,
    const float* __restrict__ x,
    const float* __restrict__ w1, const float* __restrict__ bb1,
    const float* __restrict__ lng, const float* __restrict__ lnb,
    const float* __restrict__ w2, const float* __restrict__ bb2,
    const float* __restrict__ gF, const float* __restrict__ bF,
    float* __restrict__ out, int E) {
    __shared__ float outv[4][128];
    __shared__ float buf[4][128];
    __shared__ float mu_s[4], rs_s[4];

    int t = threadIdx.x;
    int n0 = blockIdx.x * 4;
    float xres[4];

    // Phase A: out[n] = sum_e att[e] * x[col[e]]  (over this node's edge list), /100
#pragma unroll
    for (int j = 0; j < 4; ++j) {
        int n = n0 + j;
        float acc = 0.f;
        int c = cnt[n]; if (c > CAP) c = CAP;
        const int* al = adj + (size_t)n * CAP;
        for (int i = 0; i < c; ++i) {
            int e = al[i];
            float a = attv[e];
            int col = edges[E + e];
            acc += a * bf2f(xb[(size_t)col * DIM + t]);
        }
        outv[j][t] = acc * 0.01f;
        xres[j] = x[(size_t)n * DIM + t];
    }
    __syncthreads();

    // o1 = outv @ w1.T + b1
    float a1[4] = {0, 0, 0, 0};
    for (int kc = 0; kc < 128; kc += 4) {
        float4 wv = *(const float4*)&w1[(size_t)t * DIM + kc];
#pragma unroll
        for (int j = 0; j < 4; ++j)
            a1[j] += wv.x * outv[j][kc] + wv.y * outv[j][kc + 1] + wv.z * outv[j][kc + 2] + wv.w * outv[j][kc + 3];
    }
    float bias1 = bb1[t];
#pragma unroll
    for (int j = 0; j < 4; ++j) buf[j][t] = a1[j] + bias1;
    __syncthreads();

    // LN reduction 1: 32 threads per node-slot
    {
        int j = t >> 5, l = t & 31;
        float s = 0.f, q = 0.f;
#pragma unroll
        for (int i = 0; i < 4; ++i) { float v = buf[j][l + 32 * i]; s += v; q += v * v; }
#pragma unroll
        for (int off = 16; off; off >>= 1) { s += __shfl_xor(s, off); q += __shfl_xor(q, off); }
        if (l == 0) {
            float mu = s * (1.f / 128.f);
            float var = q * (1.f / 128.f) - mu * mu;
            mu_s[j] = mu; rs_s[j] = rsqrtf(var + 1e-5f);
        }
    }
    __syncthreads();

    float g = lng[t], bb = lnb[t];
    float h2[4];
#pragma unroll
    for (int j = 0; j < 4; ++j) h2[j] = fsilu((buf[j][t] - mu_s[j]) * rs_s[j] * g + bb);
    __syncthreads();
#pragma unroll
    for (int j = 0; j < 4; ++j) buf[j][t] = h2[j];
    __syncthreads();

    // o3 = h2 @ w2.T + b2 + xres
    float a3[4] = {0, 0, 0, 0};
    for (int kc = 0; kc < 128; kc += 4) {
        float4 wv = *(const float4*)&w2[(size_t)t * DIM + kc];
#pragma unroll
        for (int j = 0; j < 4; ++j)
            a3[j] += wv.x * buf[j][kc] + wv.y * buf[j][kc + 1] + wv.z * buf[j][kc + 2] + wv.w * buf[j][kc + 3];
    }
    float bias2 = bb2[t];
    float hh[4];
#pragma unroll
    for (int j = 0; j < 4; ++j) hh[j] = a3[j] + bias2 + xres[j];
    __syncthreads();
#pragma unroll
    for (int j = 0; j < 4; ++j) buf[j][t] = hh[j];
    __syncthreads();

    // LN reduction 2
    {
        int j = t >> 5, l = t & 31;
        float s = 0.f, q = 0.f;
#pragma unroll
        for (int i = 0; i < 4; ++i) { float v = buf[j][l + 32 * i]; s += v; q += v * v; }
#pragma unroll
        for (int off = 16; off; off >>= 1) { s += __shfl_xor(s, off); q += __shfl_xor(q, off); }
        if (l == 0) {
            float mu = s * (1.f / 128.f);
            float var = q * (1.f / 128.f) - mu * mu;
            mu_s[j] = mu; rs_s[j] = rsqrtf(var + 1e-5f);
        }
    }
    __syncthreads();

    float gf = gF[t], bf = bF[t];
#pragma unroll
    for (int j = 0; j < 4; ++j) {
        float y = (hh[j] - mu_s[j]) * rs_s[j] * gf + bf;
        out[(size_t)(n0 + j) * DIM + t] = fsilu(y);
    }
}

extern "C" void kernel_launch(void* const* d_in, const int* in_sizes, int n_in,
                              void* d_out, int out_size, void* d_ws, size_t ws_size,
                              hipStream_t stream) {
    const float* h         = (const float*)d_in[0];
    const float* distances = (const float*)d_in[1];
    // d_in[2] node_mask — unused by the reference
    const float* edge_mask = (const float*)d_in[3];
    const float* lin_w     = (const float*)d_in[4];
    const float* lin_b     = (const float*)d_in[5];
    const float* att_w1    = (const float*)d_in[6];
    const float* att_b1    = (const float*)d_in[7];
    const float* att_w2    = (const float*)d_in[8];
    const float* att_b2    = (const float*)d_in[9];
    const float* att_w3    = (const float*)d_in[10];
    const float* att_b3    = (const float*)d_in[11];
    const float* nm_w1     = (const float*)d_in[12];
    const float* nm_b1     = (const float*)d_in[13];
    const float* nm_ln_g   = (const float*)d_in[14];
    const float* nm_ln_b   = (const float*)d_in[15];
    const float* nm_w2     = (const float*)d_in[16];
    const float* nm_b2     = (const float*)d_in[17];
    const float* ln_g      = (const float*)d_in[18];
    const float* ln_b      = (const float*)d_in[19];
    const int*   edges     = (const int*)d_in[20];
    float* out = (float*)d_out;

    const int N = N_NODES, E = E_EDGES;

    char* ws = (char*)d_ws;
    float* x            = (float*)ws;            ws += (size_t)N * DIM * 4;
    unsigned short* xb  = (unsigned short*)ws;   ws += (size_t)N * DIM * 2;
    float* attv         = (float*)ws;            ws += (size_t)E * 4;
    int* cnt            = (int*)ws;              ws += (size_t)N * 4;
    int* adj            = (int*)ws;              ws += (size_t)N * CAP * 4;
    unsigned short* w1b = (unsigned short*)ws;   ws += 256 * 256 * 2;
    float* w1last       = (float*)ws;            ws += 256 * 4;
    unsigned short* w2b = (unsigned short*)ws;   ws += 128 * 256 * 2;

    hipMemsetAsync(cnt, 0, (size_t)N * 4, stream);

    prep_kernel<<<64, 256, 0, stream>>>(att_w1, att_w2, w1b, w1last, w2b);
    lin_kernel<<<N / 8, 128, 0, stream>>>(h, lin_w, lin_b, x, xb);
    adj_kernel<<<(E + 255) / 256, 256, 0, stream>>>(edges, cnt, adj, E);
    edge_kernel<<<E / 32, 256, 0, stream>>>(xb, distances, edge_mask, edges,
                                            w1b, w1last, att_b1, w2b, att_b2,
                                            att_w3, att_b3, attv, E);
    node_kernel<<<N / 4, 128, 0, stream>>>(attv, adj, cnt, edges, xb, x,
                                           nm_w1, nm_b1, nm_ln_g, nm_ln_b,
                                           nm_w2, nm_b2, ln_g, ln_b, out, E);
}

// Round 2
// 561.065 us; speedup vs baseline: 1.5586x; 1.5586x over previous
//
#include <hip/hip_runtime.h>
#include <hip/hip_bf16.h>

#define N_NODES 20000
#define E_EDGES 640000
#define DIM 128
#define CAP 192
#define EPB 64    // edges per block in edge_kernel
#define XST 264   // padded ushort stride for [64][256] LDS tile (16B-aligned rows, 2-way bank max)

typedef __attribute__((ext_vector_type(8))) short bf16x8;
typedef __attribute__((ext_vector_type(4))) float f32x4;

__device__ __forceinline__ float fsilu(float x) { return x / (1.f + __expf(-x)); }
__device__ __forceinline__ float fsig(float x)  { return 1.f / (1.f + __expf(-x)); }

__device__ __forceinline__ unsigned short f2bf(float x) {
    union { float f; unsigned u; } v; v.f = x;
    unsigned r = (v.u + 0x7fffu + ((v.u >> 16) & 1u)) >> 16;
    return (unsigned short)r;
}
__device__ __forceinline__ float bf2f(unsigned short s) {
    union { unsigned u; float f; } v; v.u = ((unsigned)s) << 16;
    return v.f;
}

// ---------------- Kernel 0: weight prep (fp32 -> bf16) ----------------
__global__ void prep_kernel(const float* __restrict__ w1, const float* __restrict__ w2,
                            unsigned short* __restrict__ w1b, float* __restrict__ w1last,
                            unsigned short* __restrict__ w2b) {
    int i = blockIdx.x * blockDim.x + threadIdx.x;
    int stride = gridDim.x * blockDim.x;
    for (int idx = i; idx < 256 * 256; idx += stride) {
        int o = idx >> 8, k = idx & 255;
        w1b[idx] = f2bf(w1[o * 257 + k]);
    }
    for (int idx = i; idx < 128 * 256; idx += stride)
        w2b[idx] = f2bf(w2[idx]);
    for (int idx = i; idx < 256; idx += stride)
        w1last[idx] = w1[idx * 257 + 256];
}

// ---------------- Kernel 1: x = h @ lin_w.T + lin_b (fp32 + bf16 copy) ----------------
// 128 threads = out channel, 16 nodes/block (amortize weight re-reads)
__global__ void lin_kernel(const float* __restrict__ h, const float* __restrict__ w,
                           const float* __restrict__ b, float* __restrict__ x,
                           unsigned short* __restrict__ xb) {
    __shared__ float hs[16][128];
    int t = threadIdx.x;
    int n0 = blockIdx.x * 16;
#pragma unroll
    for (int j = 0; j < 16; ++j) hs[j][t] = h[(size_t)(n0 + j) * DIM + t];
    __syncthreads();
    float acc[16];
#pragma unroll
    for (int j = 0; j < 16; ++j) acc[j] = 0.f;
    for (int kc = 0; kc < 128; kc += 4) {
        float4 wv = *(const float4*)&w[(size_t)t * DIM + kc];
#pragma unroll
        for (int j = 0; j < 16; ++j)
            acc[j] += wv.x * hs[j][kc] + wv.y * hs[j][kc + 1] + wv.z * hs[j][kc + 2] + wv.w * hs[j][kc + 3];
    }
    float bias = b[t];
#pragma unroll
    for (int j = 0; j < 16; ++j) {
        float v = acc[j] + bias;
        x[(size_t)(n0 + j) * DIM + t] = v;
        xb[(size_t)(n0 + j) * DIM + t] = f2bf(v);
    }
}

// ---------------- Kernel 3: adjacency build ----------------
__global__ void adj_kernel(const int* __restrict__ edges, int* __restrict__ cnt,
                           int* __restrict__ adj, int E) {
    int e = blockIdx.x * blockDim.x + threadIdx.x;
    if (e < E) {
        int r = edges[e];  // row
        int slot = atomicAdd(&cnt[r], 1);
        if (slot < CAP) adj[(size_t)r * CAP + slot] = e;
    }
}

// ---------------- Kernel 2: edge MLP -> att[E] ----------------
// 512 threads (8 waves), 64 edges/block. Waves split the N (output) dim.
// Single [64][XST] LDS tile: holds xcat during layer1, then a1 (acc1 bridges in regs).
__global__ __launch_bounds__(512, 4) void edge_kernel(
    const unsigned short* __restrict__ xb,
    const float* __restrict__ dist, const float* __restrict__ emask,
    const int* __restrict__ edges,
    const unsigned short* __restrict__ w1b, const float* __restrict__ w1last,
    const float* __restrict__ b1,
    const unsigned short* __restrict__ w2b, const float* __restrict__ b2,
    const float* __restrict__ w3, const float* __restrict__ b3v,
    float* __restrict__ att, int E) {
    __shared__ unsigned short buf[EPB * XST];   // xcat, then a1 (aliased)
    __shared__ float part[8][EPB];              // per-wave layer3 partials
    __shared__ float dvals[EPB];
    __shared__ int ridx[EPB], cidx[EPB];

    int tid = threadIdx.x;
    int eb = blockIdx.x * EPB;

    if (tid < EPB) {
        int e = eb + tid;
        ridx[tid] = edges[e];
        cidx[tid] = edges[E + e];
        dvals[tid] = dist[e] * emask[e];
    }
    __syncthreads();

    // gather x_cat = [x[row] | x[col]] as bf16, 16B chunks: 2048 chunks / 512 threads
#pragma unroll
    for (int i = 0; i < 4; ++i) {
        int c = tid + 512 * i;
        int r = c >> 5;
        int cb = (c & 31) * 8;
        const unsigned short* src;
        if (cb < 128) src = xb + (size_t)ridx[r] * DIM + cb;
        else          src = xb + (size_t)cidx[r] * DIM + (cb - 128);
        *(bf16x8*)&buf[r * XST + cb] = *(const bf16x8*)src;
    }
    __syncthreads();

    int wave = tid >> 6, lane = tid & 63;
    int lrow = lane & 15, quad = lane >> 4;

    // ---- layer 1: a1 = silu(xcat @ W1^T + b1 + d*w1last); wave covers 32 of 256 N
    f32x4 z = {0.f, 0.f, 0.f, 0.f};
    f32x4 acc1[4][2];
#pragma unroll
    for (int mt = 0; mt < 4; ++mt)
#pragma unroll
        for (int nt = 0; nt < 2; ++nt) acc1[mt][nt] = z;

    int nb = wave * 32;
    for (int kk = 0; kk < 8; ++kk) {
        int ka = kk * 32 + quad * 8;
        bf16x8 a[4];
#pragma unroll
        for (int mt = 0; mt < 4; ++mt)
            a[mt] = *(bf16x8*)&buf[(mt * 16 + lrow) * XST + ka];
#pragma unroll
        for (int nt = 0; nt < 2; ++nt) {
            int n = nb + nt * 16 + lrow;
            bf16x8 bfrag = *(const bf16x8*)&w1b[(size_t)n * 256 + ka];
#pragma unroll
            for (int mt = 0; mt < 4; ++mt)
                acc1[mt][nt] = __builtin_amdgcn_mfma_f32_16x16x32_bf16(a[mt], bfrag, acc1[mt][nt], 0, 0, 0);
        }
    }
    __syncthreads();   // all waves done reading xcat; buf becomes a1

#pragma unroll
    for (int nt = 0; nt < 2; ++nt) {
        int n = nb + nt * 16 + lrow;
        float bias = b1[n];
        float wl = w1last[n];
#pragma unroll
        for (int mt = 0; mt < 4; ++mt) {
#pragma unroll
            for (int r = 0; r < 4; ++r) {
                int m = mt * 16 + quad * 4 + r;
                float v = acc1[mt][nt][r] + bias + dvals[m] * wl;
                buf[m * XST + n] = f2bf(fsilu(v));
            }
        }
    }
    __syncthreads();

    // ---- layer 2: a2 = silu(a1 @ W2^T + b2); wave covers 16 of 128 N (n = wave*16+lrow)
    f32x4 acc2[4];
#pragma unroll
    for (int mt = 0; mt < 4; ++mt) acc2[mt] = z;

    int n2 = wave * 16 + lrow;
    for (int kk = 0; kk < 8; ++kk) {
        int ka = kk * 32 + quad * 8;
        bf16x8 bfrag = *(const bf16x8*)&w2b[(size_t)n2 * 256 + ka];
#pragma unroll
        for (int mt = 0; mt < 4; ++mt) {
            bf16x8 a = *(bf16x8*)&buf[(mt * 16 + lrow) * XST + ka];
            acc2[mt] = __builtin_amdgcn_mfma_f32_16x16x32_bf16(a, bfrag, acc2[mt], 0, 0, 0);
        }
    }

    // ---- layer 3 in registers: s[m] = sum_n silu(a2[m][n]) * w3[n]
    float bias2 = b2[n2];
    float w3v = w3[n2];
    float s[4][4];
#pragma unroll
    for (int mt = 0; mt < 4; ++mt)
#pragma unroll
        for (int r = 0; r < 4; ++r)
            s[mt][r] = fsilu(acc2[mt][r] + bias2) * w3v;
    // reduce over lrow (lane bits 0..3): each lane holds one n
#pragma unroll
    for (int off = 1; off < 16; off <<= 1) {
#pragma unroll
        for (int mt = 0; mt < 4; ++mt)
#pragma unroll
            for (int r = 0; r < 4; ++r)
                s[mt][r] += __shfl_xor(s[mt][r], off);
    }
    if (lrow == 0) {
#pragma unroll
        for (int mt = 0; mt < 4; ++mt)
#pragma unroll
            for (int r = 0; r < 4; ++r)
                part[wave][mt * 16 + quad * 4 + r] = s[mt][r];
    }
    __syncthreads();

    if (tid < EPB) {
        float ssum = b3v[0];
#pragma unroll
        for (int w = 0; w < 8; ++w) ssum += part[w][tid];
        att[eb + tid] = fsig(ssum) * emask[eb + tid];
    }
}

// ---------------- Kernel 4: aggregate + node MLP + LNs ----------------
// 128 threads (thread = channel), 4 nodes per block
__global__ void node_kernel(
    const float* __restrict__ attv, const int* __restrict__ adj, const int* __restrict__ cnt,
    const int* __restrict__ edges, const unsigned short* __restrict__ xb,
    const float* __restrict__ x,
    const float* __restrict__ w1, const float* __restrict__ bb1,
    const float* __restrict__ lng, const float* __restrict__ lnb,
    const float* __restrict__ w2, const float* __restrict__ bb2,
    const float* __restrict__ gF, const float* __restrict__ bF,
    float* __restrict__ out, int E) {
    __shared__ float outv[4][128];
    __shared__ float bufs[4][128];
    __shared__ float mu_s[4], rs_s[4];
    __shared__ float atts[CAP];
    __shared__ int cols[CAP];

    int t = threadIdx.x;
    int n0 = blockIdx.x * 4;
    float xres[4];

    // Phase A: out[n] = (sum_e att[e] * x[col[e]]) / 100, per node's edge list
#pragma unroll
    for (int j = 0; j < 4; ++j) {
        int n = n0 + j;
        int c = cnt[n]; if (c > CAP) c = CAP;
        const int* al = adj + (size_t)n * CAP;
        for (int i = t; i < c; i += 128) {
            int e = al[i];
            atts[i] = attv[e];
            cols[i] = edges[E + e];
        }
        __syncthreads();
        float a0 = 0.f, a1v = 0.f, a2v = 0.f, a3v = 0.f;
        int i = 0;
        for (; i + 4 <= c; i += 4) {
            a0  += atts[i]     * bf2f(xb[(size_t)cols[i]     * DIM + t]);
            a1v += atts[i + 1] * bf2f(xb[(size_t)cols[i + 1] * DIM + t]);
            a2v += atts[i + 2] * bf2f(xb[(size_t)cols[i + 2] * DIM + t]);
            a3v += atts[i + 3] * bf2f(xb[(size_t)cols[i + 3] * DIM + t]);
        }
        for (; i < c; ++i)
            a0 += atts[i] * bf2f(xb[(size_t)cols[i] * DIM + t]);
        outv[j][t] = (a0 + a1v + a2v + a3v) * 0.01f;
        xres[j] = x[(size_t)n * DIM + t];
        __syncthreads();
    }

    // o1 = outv @ w1.T + b1
    float a1[4] = {0, 0, 0, 0};
    for (int kc = 0; kc < 128; kc += 4) {
        float4 wv = *(const float4*)&w1[(size_t)t * DIM + kc];
#pragma unroll
        for (int j = 0; j < 4; ++j)
            a1[j] += wv.x * outv[j][kc] + wv.y * outv[j][kc + 1] + wv.z * outv[j][kc + 2] + wv.w * outv[j][kc + 3];
    }
    float bias1 = bb1[t];
#pragma unroll
    for (int j = 0; j < 4; ++j) bufs[j][t] = a1[j] + bias1;
    __syncthreads();

    // LN reduction 1
    {
        int j = t >> 5, l = t & 31;
        float s = 0.f, q = 0.f;
#pragma unroll
        for (int i = 0; i < 4; ++i) { float v = bufs[j][l + 32 * i]; s += v; q += v * v; }
#pragma unroll
        for (int off = 16; off; off >>= 1) { s += __shfl_xor(s, off); q += __shfl_xor(q, off); }
        if (l == 0) {
            float mu = s * (1.f / 128.f);
            float var = q * (1.f / 128.f) - mu * mu;
            mu_s[j] = mu; rs_s[j] = rsqrtf(var + 1e-5f);
        }
    }
    __syncthreads();

    float g = lng[t], bb = lnb[t];
    float h2[4];
#pragma unroll
    for (int j = 0; j < 4; ++j) h2[j] = fsilu((bufs[j][t] - mu_s[j]) * rs_s[j] * g + bb);
    __syncthreads();
#pragma unroll
    for (int j = 0; j < 4; ++j) bufs[j][t] = h2[j];
    __syncthreads();

    // o3 = h2 @ w2.T + b2 + xres
    float a3[4] = {0, 0, 0, 0};
    for (int kc = 0; kc < 128; kc += 4) {
        float4 wv = *(const float4*)&w2[(size_t)t * DIM + kc];
#pragma unroll
        for (int j = 0; j < 4; ++j)
            a3[j] += wv.x * bufs[j][kc] + wv.y * bufs[j][kc + 1] + wv.z * bufs[j][kc + 2] + wv.w * bufs[j][kc + 3];
    }
    float bias2 = bb2[t];
    float hh[4];
#pragma unroll
    for (int j = 0; j < 4; ++j) hh[j] = a3[j] + bias2 + xres[j];
    __syncthreads();
#pragma unroll
    for (int j = 0; j < 4; ++j) bufs[j][t] = hh[j];
    __syncthreads();

    // LN reduction 2
    {
        int j = t >> 5, l = t & 31;
        float s = 0.f, q = 0.f;
#pragma unroll
        for (int i = 0; i < 4; ++i) { float v = bufs[j][l + 32 * i]; s += v; q += v * v; }
#pragma unroll
        for (int off = 16; off; off >>= 1) { s += __shfl_xor(s, off); q += __shfl_xor(q, off); }
        if (l == 0) {
            float mu = s * (1.f / 128.f);
            float var = q * (1.f / 128.f) - mu * mu;
            mu_s[j] = mu; rs_s[j] = rsqrtf(var + 1e-5f);
        }
    }
    __syncthreads();

    float gf = gF[t], bf = bF[t];
#pragma unroll
    for (int j = 0; j < 4; ++j) {
        float y = (hh[j] - mu_s[j]) * rs_s[j] * gf + bf;
        out[(size_t)(n0 + j) * DIM + t] = fsilu(y);
    }
}

extern "C" void kernel_launch(void* const* d_in, const int* in_sizes, int n_in,
                              void* d_out, int out_size, void* d_ws, size_t ws_size,
                              hipStream_t stream) {
    const float* h         = (const float*)d_in[0];
    const float* distances = (const float*)d_in[1];
    const float* edge_mask = (const float*)d_in[3];
    const float* lin_w     = (const float*)d_in[4];
    const float* lin_b     = (const float*)d_in[5];
    const float* att_w1    = (const float*)d_in[6];
    const float* att_b1    = (const float*)d_in[7];
    const float* att_w2    = (const float*)d_in[8];
    const float* att_b2    = (const float*)d_in[9];
    const float* att_w3    = (const float*)d_in[10];
    const float* att_b3    = (const float*)d_in[11];
    const float* nm_w1     = (const float*)d_in[12];
    const float* nm_b1     = (const float*)d_in[13];
    const float* nm_ln_g   = (const float*)d_in[14];
    const float* nm_ln_b   = (const float*)d_in[15];
    const float* nm_w2     = (const float*)d_in[16];
    const float* nm_b2     = (const float*)d_in[17];
    const float* ln_g      = (const float*)d_in[18];
    const float* ln_b      = (const float*)d_in[19];
    const int*   edges     = (const int*)d_in[20];
    float* out = (float*)d_out;

    const int N = N_NODES, E = E_EDGES;

    char* ws = (char*)d_ws;
    float* x            = (float*)ws;            ws += (size_t)N * DIM * 4;
    unsigned short* xb  = (unsigned short*)ws;   ws += (size_t)N * DIM * 2;
    float* attv         = (float*)ws;            ws += (size_t)E * 4;
    int* cnt            = (int*)ws;              ws += (size_t)N * 4;
    int* adj            = (int*)ws;              ws += (size_t)N * CAP * 4;
    unsigned short* w1b = (unsigned short*)ws;   ws += 256 * 256 * 2;
    float* w1last       = (float*)ws;            ws += 256 * 4;
    unsigned short* w2b = (unsigned short*)ws;   ws += 128 * 256 * 2;

    hipMemsetAsync(cnt, 0, (size_t)N * 4, stream);

    prep_kernel<<<64, 256, 0, stream>>>(att_w1, att_w2, w1b, w1last, w2b);
    lin_kernel<<<N / 16, 128, 0, stream>>>(h, lin_w, lin_b, x, xb);
    adj_kernel<<<(E + 255) / 256, 256, 0, stream>>>(edges, cnt, adj, E);
    edge_kernel<<<E / EPB, 512, 0, stream>>>(xb, distances, edge_mask, edges,
                                             w1b, w1last, att_b1, w2b, att_b2,
                                             att_w3, att_b3, attv, E);
    node_kernel<<<N / 4, 128, 0, stream>>>(attv, adj, cnt, edges, xb, x,
                                           nm_w1, nm_b1, nm_ln_g, nm_ln_b,
                                           nm_w2, nm_b2, ln_g, ln_b, out, E);
}